// Round 1
// baseline (136.683 us; speedup 1.0000x reference)
//
#include <hip/hip_runtime.h>
#include <math.h>

#define Bn 32
#define Cn 256
#define Hn 64
#define Wn 64
#define HWn (Hn * Wn)      // 4096
#define MIDn 16
#define Kn 7
#define PADn 3

// -------- Kernel 1: per-(b,c) mean & max over H*W --------
// grid = B*C blocks, 256 threads
__global__ void pool_kernel(const float* __restrict__ x,
                            float* __restrict__ avg, float* __restrict__ mx) {
    int bc = blockIdx.x;
    const float4* xp4 = (const float4*)(x + (size_t)bc * HWn);
    int t = threadIdx.x;
    float s = 0.f, m = -INFINITY;
    #pragma unroll
    for (int i = 0; i < 4; ++i) {           // 1024 float4 / 256 threads
        float4 v = xp4[t + i * 256];
        s += v.x + v.y + v.z + v.w;
        m = fmaxf(m, fmaxf(fmaxf(v.x, v.y), fmaxf(v.z, v.w)));
    }
    #pragma unroll
    for (int off = 32; off > 0; off >>= 1) {
        s += __shfl_down(s, off);
        m = fmaxf(m, __shfl_down(m, off));
    }
    __shared__ float ss[4], smx[4];
    int wave = t >> 6, lane = t & 63;
    if (lane == 0) { ss[wave] = s; smx[wave] = m; }
    __syncthreads();
    if (t == 0) {
        float S = ss[0] + ss[1] + ss[2] + ss[3];
        float M = fmaxf(fmaxf(smx[0], smx[1]), fmaxf(smx[2], smx[3]));
        avg[bc] = S * (1.f / (float)HWn);
        mx[bc]  = M;
    }
}

// -------- Kernel 2: MLP + sigmoid -> ca[B,C] --------
// grid = B blocks, 256 threads (one per channel)
__global__ void mlp_kernel(const float* __restrict__ avg, const float* __restrict__ mx,
                           const float* __restrict__ w1, const float* __restrict__ w2,
                           float* __restrict__ ca) {
    int b = blockIdx.x;
    int t = threadIdx.x;
    __shared__ float sv[Cn], sx[Cn], h[2 * MIDn];
    sv[t] = avg[b * Cn + t];
    sx[t] = mx[b * Cn + t];
    __syncthreads();
    if (t < 2 * MIDn) {
        int m = t & (MIDn - 1);
        const float* src = (t < MIDn) ? sv : sx;
        const float* wr = w1 + m * Cn;
        float acc = 0.f;
        for (int c = 0; c < Cn; ++c) acc += src[c] * wr[c];
        h[t] = fmaxf(acc, 0.f);               // relu
    }
    __syncthreads();
    float acc = 0.f;
    #pragma unroll
    for (int m = 0; m < MIDn; ++m)
        acc += (h[m] + h[MIDn + m]) * w2[t * MIDn + m];
    ca[b * Cn + t] = 1.f / (1.f + expf(-acc));
}

// -------- Kernel 3: per-pixel channel mean/max of x*ca -> feat --------
// grid = B * (HW/1024) = 128 blocks, 256 threads, 4 pixels (float4) per thread
__global__ void feat_kernel(const float* __restrict__ x, const float* __restrict__ ca,
                            float* __restrict__ fmean, float* __restrict__ fmax) {
    int blk = blockIdx.x;
    int b = blk >> 2;                 // 4 blocks per batch
    int p0 = (blk & 3) * 1024 + threadIdx.x * 4;
    const float* xb = x + (size_t)b * Cn * HWn + p0;
    float4 s = {0.f, 0.f, 0.f, 0.f};
    float4 m = {-INFINITY, -INFINITY, -INFINITY, -INFINITY};
    const float* cab = ca + b * Cn;
    for (int c = 0; c < Cn; ++c) {
        float a = cab[c];
        float4 v = *(const float4*)(xb + (size_t)c * HWn);
        v.x *= a; v.y *= a; v.z *= a; v.w *= a;
        s.x += v.x; s.y += v.y; s.z += v.z; s.w += v.w;
        m.x = fmaxf(m.x, v.x); m.y = fmaxf(m.y, v.y);
        m.z = fmaxf(m.z, v.z); m.w = fmaxf(m.w, v.w);
    }
    const float inv = 1.f / (float)Cn;
    float4 mean4 = {s.x * inv, s.y * inv, s.z * inv, s.w * inv};
    *(float4*)(fmean + b * HWn + p0) = mean4;
    *(float4*)(fmax + b * HWn + p0) = m;
}

// -------- Kernel 4: 7x7 conv on [2,H,W] feat + sigmoid -> smap[B,HW] --------
// grid = B blocks, 256 threads; feat staged in LDS
__global__ void conv_kernel(const float* __restrict__ fmean, const float* __restrict__ fmax,
                            const float* __restrict__ wsp, float* __restrict__ smap) {
    int b = blockIdx.x;
    __shared__ float sm[HWn];
    __shared__ float sx[HWn];
    __shared__ float wgt[2 * Kn * Kn];
    for (int i = threadIdx.x; i < HWn / 4; i += 256) {
        ((float4*)sm)[i] = ((const float4*)(fmean + b * HWn))[i];
        ((float4*)sx)[i] = ((const float4*)(fmax + b * HWn))[i];
    }
    if (threadIdx.x < 2 * Kn * Kn) wgt[threadIdx.x] = wsp[threadIdx.x];
    __syncthreads();
    for (int p = threadIdx.x; p < HWn; p += 256) {
        int h = p >> 6, w = p & 63;
        float acc = 0.f;
        #pragma unroll
        for (int kh = 0; kh < Kn; ++kh) {
            int hh = h + kh - PADn;
            if (hh < 0 || hh >= Hn) continue;
            #pragma unroll
            for (int kw = 0; kw < Kn; ++kw) {
                int ww = w + kw - PADn;
                if (ww < 0 || ww >= Wn) continue;
                float wm = wgt[kh * Kn + kw];
                float wx = wgt[Kn * Kn + kh * Kn + kw];
                acc += sm[hh * Wn + ww] * wm + sx[hh * Wn + ww] * wx;
            }
        }
        smap[b * HWn + p] = 1.f / (1.f + expf(-acc));
    }
}

// -------- Kernel 5: out = x * ca * smap --------
// grid over float4 elements: B*C*HW/4 / 256 blocks
__global__ void out_kernel(const float* __restrict__ x, const float* __restrict__ ca,
                           const float* __restrict__ smap, float* __restrict__ out) {
    size_t i4 = (size_t)blockIdx.x * 256 + threadIdx.x;
    size_t i = i4 * 4;
    int b = (int)(i / ((size_t)Cn * HWn));
    int c = (int)((i / HWn) % Cn);
    int p = (int)(i % HWn);
    float a = ca[b * Cn + c];
    float4 v = ((const float4*)x)[i4];
    float4 s4 = *(const float4*)(smap + b * HWn + p);
    float4 o = {v.x * a * s4.x, v.y * a * s4.y, v.z * a * s4.z, v.w * a * s4.w};
    ((float4*)out)[i4] = o;
}

extern "C" void kernel_launch(void* const* d_in, const int* in_sizes, int n_in,
                              void* d_out, int out_size, void* d_ws, size_t ws_size,
                              hipStream_t stream) {
    const float* x  = (const float*)d_in[0];
    const float* w1 = (const float*)d_in[1];
    const float* w2 = (const float*)d_in[2];
    const float* ws = (const float*)d_in[3];
    float* out = (float*)d_out;

    float* wsf   = (float*)d_ws;
    float* avg   = wsf;                      // B*C       = 8192
    float* mx    = avg + Bn * Cn;            // 8192
    float* ca    = mx + Bn * Cn;             // 8192
    float* fmean = ca + Bn * Cn;             // B*HW      = 131072
    float* fmax  = fmean + Bn * HWn;         // 131072
    float* smap  = fmax + Bn * HWn;          // 131072

    pool_kernel<<<Bn * Cn, 256, 0, stream>>>(x, avg, mx);
    mlp_kernel<<<Bn, 256, 0, stream>>>(avg, mx, w1, w2, ca);
    feat_kernel<<<Bn * (HWn / 1024), 256, 0, stream>>>(x, ca, fmean, fmax);
    conv_kernel<<<Bn, 256, 0, stream>>>(fmean, fmax, ws, smap);
    out_kernel<<<(Bn * Cn * HWn / 4) / 256, 256, 0, stream>>>(x, ca, smap, out);
}

// Round 3
// 105.254 us; speedup vs baseline: 1.2986x; 1.2986x over previous
//
#include <hip/hip_runtime.h>
#include <math.h>

#define Bn 32
#define Cn 256
#define Hn 64
#define Wn 64
#define HWn (Hn * Wn)      // 4096
#define MIDn 16
#define Kn 7
#define PADn 3

typedef float vf4 __attribute__((ext_vector_type(4)));

// -------- Kernel 1: per-(b,c) mean & max over H*W --------
// grid = B*C blocks, 256 threads
__global__ void pool_kernel(const float* __restrict__ x,
                            float* __restrict__ avg, float* __restrict__ mx) {
    int bc = blockIdx.x;
    const float4* xp4 = (const float4*)(x + (size_t)bc * HWn);
    int t = threadIdx.x;
    float s = 0.f, m = -INFINITY;
    #pragma unroll
    for (int i = 0; i < 4; ++i) {           // 1024 float4 / 256 threads
        float4 v = xp4[t + i * 256];
        s += v.x + v.y + v.z + v.w;
        m = fmaxf(m, fmaxf(fmaxf(v.x, v.y), fmaxf(v.z, v.w)));
    }
    #pragma unroll
    for (int off = 32; off > 0; off >>= 1) {
        s += __shfl_down(s, off);
        m = fmaxf(m, __shfl_down(m, off));
    }
    __shared__ float ss[4], smx[4];
    int wave = t >> 6, lane = t & 63;
    if (lane == 0) { ss[wave] = s; smx[wave] = m; }
    __syncthreads();
    if (t == 0) {
        float S = ss[0] + ss[1] + ss[2] + ss[3];
        float M = fmaxf(fmaxf(smx[0], smx[1]), fmaxf(smx[2], smx[3]));
        avg[bc] = S * (1.f / (float)HWn);
        mx[bc]  = M;
    }
}

// -------- Kernel 2: MLP + sigmoid -> ca[B,C] --------
// grid = B blocks, 256 threads (one per channel)
__global__ void mlp_kernel(const float* __restrict__ avg, const float* __restrict__ mx,
                           const float* __restrict__ w1, const float* __restrict__ w2,
                           float* __restrict__ ca) {
    int b = blockIdx.x;
    int t = threadIdx.x;
    __shared__ float sv[Cn], sx[Cn], h[2 * MIDn];
    sv[t] = avg[b * Cn + t];
    sx[t] = mx[b * Cn + t];
    __syncthreads();
    if (t < 2 * MIDn) {
        int m = t & (MIDn - 1);
        const float* src = (t < MIDn) ? sv : sx;
        const float* wr = w1 + m * Cn;
        float acc = 0.f;
        for (int c = 0; c < Cn; ++c) acc += src[c] * wr[c];
        h[t] = fmaxf(acc, 0.f);               // relu
    }
    __syncthreads();
    float acc = 0.f;
    #pragma unroll
    for (int m = 0; m < MIDn; ++m)
        acc += (h[m] + h[MIDn + m]) * w2[t * MIDn + m];
    ca[b * Cn + t] = 1.f / (1.f + expf(-acc));
}

// -------- Kernel 3: per-pixel channel mean/max of x*ca -> feat --------
// grid = B*16 = 512 blocks, 256 threads = (64 float4-pixels) x (4 channel-quarters)
__global__ void feat_kernel(const float* __restrict__ x, const float* __restrict__ ca,
                            float* __restrict__ fmean, float* __restrict__ fmax) {
    int blk = blockIdx.x;
    int b = blk >> 4;                          // 16 blocks per batch
    int ptile = (blk & 15) * 256;              // 256 pixels per block
    int tx = threadIdx.x & 63;                 // float4 index (64 * 4 = 256 pixels)
    int ty = threadIdx.x >> 6;                 // channel quarter 0..3
    const float* xb = x + (size_t)b * Cn * HWn + ptile + tx * 4;
    const float* cab = ca + b * Cn;
    float4 s = {0.f, 0.f, 0.f, 0.f};
    float4 m = {-INFINITY, -INFINITY, -INFINITY, -INFINITY};
    int c0 = ty * 64;
    for (int c = c0; c < c0 + 64; ++c) {
        float a = cab[c];
        float4 v = *(const float4*)(xb + (size_t)c * HWn);
        v.x *= a; v.y *= a; v.z *= a; v.w *= a;
        s.x += v.x; s.y += v.y; s.z += v.z; s.w += v.w;
        m.x = fmaxf(m.x, v.x); m.y = fmaxf(m.y, v.y);
        m.z = fmaxf(m.z, v.z); m.w = fmaxf(m.w, v.w);
    }
    __shared__ float4 lsum[4][64];
    __shared__ float4 lmax[4][64];
    lsum[ty][tx] = s; lmax[ty][tx] = m;
    __syncthreads();
    if (ty == 0) {
        #pragma unroll
        for (int q = 1; q < 4; ++q) {
            float4 s2 = lsum[q][tx], m2 = lmax[q][tx];
            s.x += s2.x; s.y += s2.y; s.z += s2.z; s.w += s2.w;
            m.x = fmaxf(m.x, m2.x); m.y = fmaxf(m.y, m2.y);
            m.z = fmaxf(m.z, m2.z); m.w = fmaxf(m.w, m2.w);
        }
        const float inv = 1.f / (float)Cn;
        float4 mean4 = {s.x * inv, s.y * inv, s.z * inv, s.w * inv};
        *(float4*)(fmean + b * HWn + ptile + tx * 4) = mean4;
        *(float4*)(fmax  + b * HWn + ptile + tx * 4) = m;
    }
}

// -------- Kernel 4: 7x7 conv on [2,H,W] feat + sigmoid -> smap[B,HW] --------
// grid = B*4 = 128 blocks (16-row stripes), 256 threads; stripe+halo staged in LDS
__global__ void conv_kernel(const float* __restrict__ fmean, const float* __restrict__ fmax,
                            const float* __restrict__ wsp, float* __restrict__ smap) {
    int blk = blockIdx.x;
    int b = blk >> 2;
    int r0 = (blk & 3) * 16;
    __shared__ float sm[22][64];
    __shared__ float sx[22][64];
    __shared__ float wgt[2 * Kn * Kn];
    int t = threadIdx.x;
    if (t < 2 * Kn * Kn) wgt[t] = wsp[t];
    for (int i = t; i < 22 * 64; i += 256) {
        int rr = r0 - PADn + (i >> 6);
        int cc = i & 63;
        float vm = 0.f, vx = 0.f;
        if (rr >= 0 && rr < Hn) {
            vm = fmean[b * HWn + rr * Wn + cc];
            vx = fmax[b * HWn + rr * Wn + cc];
        }
        sm[i >> 6][cc] = vm;
        sx[i >> 6][cc] = vx;
    }
    __syncthreads();
    for (int p = t; p < 16 * Wn; p += 256) {
        int h = p >> 6, w = p & 63;           // local row 0..15
        float acc = 0.f;
        #pragma unroll
        for (int kh = 0; kh < Kn; ++kh) {
            #pragma unroll
            for (int kw = 0; kw < Kn; ++kw) {
                int ww = w + kw - PADn;
                if (ww < 0 || ww >= Wn) continue;
                acc += sm[h + kh][ww] * wgt[kh * Kn + kw]
                     + sx[h + kh][ww] * wgt[Kn * Kn + kh * Kn + kw];
            }
        }
        smap[b * HWn + (r0 + h) * Wn + w] = 1.f / (1.f + expf(-acc));
    }
}

// -------- Kernel 5: out = x * ca * smap (non-temporal store) --------
__global__ void out_kernel(const float* __restrict__ x, const float* __restrict__ ca,
                           const float* __restrict__ smap, float* __restrict__ out) {
    size_t i4 = (size_t)blockIdx.x * 256 + threadIdx.x;
    size_t i = i4 * 4;
    int b = (int)(i >> 20);                   // / (C*HW) = 2^20
    int c = (int)((i >> 12) & (Cn - 1));      // / HW % C
    int p = (int)(i & (HWn - 1));
    float a = ca[b * Cn + c];
    float4 v = ((const float4*)x)[i4];
    float4 s4 = *(const float4*)(smap + b * HWn + p);
    vf4 o = {v.x * a * s4.x, v.y * a * s4.y, v.z * a * s4.z, v.w * a * s4.w};
    __builtin_nontemporal_store(o, (vf4*)out + i4);
}

extern "C" void kernel_launch(void* const* d_in, const int* in_sizes, int n_in,
                              void* d_out, int out_size, void* d_ws, size_t ws_size,
                              hipStream_t stream) {
    const float* x  = (const float*)d_in[0];
    const float* w1 = (const float*)d_in[1];
    const float* w2 = (const float*)d_in[2];
    const float* ws = (const float*)d_in[3];
    float* out = (float*)d_out;

    float* wsf   = (float*)d_ws;
    float* avg   = wsf;                      // B*C       = 8192
    float* mx    = avg + Bn * Cn;            // 8192
    float* ca    = mx + Bn * Cn;             // 8192
    float* fmean = ca + Bn * Cn;             // B*HW      = 131072
    float* fmax  = fmean + Bn * HWn;         // 131072
    float* smap  = fmax + Bn * HWn;          // 131072

    pool_kernel<<<Bn * Cn, 256, 0, stream>>>(x, avg, mx);
    mlp_kernel<<<Bn, 256, 0, stream>>>(avg, mx, w1, w2, ca);
    feat_kernel<<<Bn * 16, 256, 0, stream>>>(x, ca, fmean, fmax);
    conv_kernel<<<Bn * 4, 256, 0, stream>>>(fmean, fmax, ws, smap);
    out_kernel<<<(Bn * Cn * HWn / 4) / 256, 256, 0, stream>>>(x, ca, smap, out);
}